// Round 7
// baseline (67.842 us; speedup 1.0000x reference)
//
#include <hip/hip_runtime.h>
#include <math.h>

#define NB 16
#define NL 4096
#define NC 512
#define NC4 128          // NC/4 float4 per row
#define NKEEP 2458       // ceil(4096*0.6)
#define KEEPB 76         // first k_perm block with tail rows (76*32 = 2432)
#define NTAILB 52        // 128 - 76 partial slots per batch

typedef float f32x4 __attribute__((ext_vector_type(4)));

// ---------------- ws layout ----------------
// key     u64 [NB][NL]          @ 0        (512 KB)
// rank    i32 [NB][NL]          @ 524288   (256 KB)
// w       f32 [NB][NL]          @ 786432   (256 KB) unnormalized exp, 0 for keep
// order   i32 [NB][NL]          @ 1048576  (256 KB) inverse permutation
// partial f32 [NB][52][512]     @ 1310720  (1.66 MB)
// scalars                       @ 3145728  alpha[16] beta[16] smaxu[16] Zpart[256]

// Kernel 1: per-batch front-end. Wave 0: bit-exact np pairwise mean
// (PW_BLOCKSIZE=128, 8-acc base, butterfly combine) -> alpha/beta.
// Then all 1024 threads: sort keys (mul,mul,add, no FMA), zero rank,
// block-reduce score max -> smaxu (plain store, no atomics).
__global__ void __launch_bounds__(1024) k_front(const float* __restrict__ ax,
                                                const float* __restrict__ ay,
                                                unsigned long long* __restrict__ key,
                                                int* __restrict__ rank,
                                                float* __restrict__ alpha,
                                                float* __restrict__ beta,
                                                unsigned* __restrict__ smaxu) {
  int b = blockIdx.x;
  int tid = threadIdx.x;
  __shared__ float s_ab[2];
  __shared__ unsigned redmaxu[16];
  if (tid < 64) {
    int lane = tid;
    float sx = 0.0f, sy = 0.0f;
    if (lane < 32) {
      const float* px = ax + b * NL + lane * 128;
      const float* py = ay + b * NL + lane * 128;
      float r[8], q[8];
#pragma unroll
      for (int j = 0; j < 8; ++j) { r[j] = px[j]; q[j] = py[j]; }
      for (int i = 8; i < 128; i += 8) {
#pragma unroll
        for (int j = 0; j < 8; ++j) {
          r[j] = __fadd_rn(r[j], px[i + j]);
          q[j] = __fadd_rn(q[j], py[i + j]);
        }
      }
      sx = __fadd_rn(__fadd_rn(__fadd_rn(r[0], r[1]), __fadd_rn(r[2], r[3])),
                     __fadd_rn(__fadd_rn(r[4], r[5]), __fadd_rn(r[6], r[7])));
      sy = __fadd_rn(__fadd_rn(__fadd_rn(q[0], q[1]), __fadd_rn(q[2], q[3])),
                     __fadd_rn(__fadd_rn(q[4], q[5]), __fadd_rn(q[6], q[7])));
    }
#pragma unroll
    for (int m = 1; m <= 16; m <<= 1) {
      sx = __fadd_rn(sx, __shfl_xor(sx, m, 64));
      sy = __fadd_rn(sy, __shfl_xor(sy, m, 64));
    }
    if (lane == 0) {
      float mx = __fdiv_rn(sx, 4096.0f);
      float my = __fdiv_rn(sy, 4096.0f);
      float cov = __fdiv_rn(my, __fadd_rn(mx, 1e-6f));
      float z = __fsub_rn(1.0f, cov);
      double a = 1.0 / (1.0 + exp(-(double)z));   // correctly-rounded sigmoid
      float af = (float)a;
      alpha[b] = af;
      beta[b] = __fsub_rn(1.0f, af);
      s_ab[0] = af;
      s_ab[1] = __fsub_rn(1.0f, af);
    }
  }
  __syncthreads();
  float af = s_ab[0], bf = s_ab[1];
  unsigned m = 0;   // real max su > 0x80000000 (max score > 0), so 0 is safe
#pragma unroll
  for (int p = 0; p < 4; ++p) {
    int l = p * 1024 + tid;
    int idx = b * NL + l;
    float s = __fadd_rn(__fmul_rn(af, ax[idx]), __fmul_rn(bf, ay[idx]));
    unsigned u = __float_as_uint(s);
    unsigned su = u ^ ((u & 0x80000000u) ? 0xFFFFFFFFu : 0x80000000u);
    key[idx] = ((unsigned long long)(~su) << 32) | (unsigned)l;  // stable descending
    rank[idx] = 0;
    m = (su > m) ? su : m;
  }
#pragma unroll
  for (int d = 1; d < 64; d <<= 1) {
    unsigned o = (unsigned)__shfl_xor((int)m, d, 64);
    m = (o > m) ? o : m;
  }
  if ((tid & 63) == 0) redmaxu[tid >> 6] = m;
  __syncthreads();
  if (tid == 0) {
    unsigned M = redmaxu[0];
#pragma unroll
    for (int k = 1; k < 16; ++k) M = (redmaxu[k] > M) ? redmaxu[k] : M;
    smaxu[b] = M;
  }
}

// Kernel 2: rank(i) = #{j : key_j < key_i}. Register-blocked 4 i-keys/thread,
// 512-key j-tile in LDS read as broadcast ulonglong2. grid (4, 8, NB).
__global__ void __launch_bounds__(256) k_rank(const unsigned long long* __restrict__ key,
                                              int* __restrict__ rank) {
  __shared__ unsigned long long tile[512];
  int b = blockIdx.z;
  int tid = threadIdx.x;
  const unsigned long long* kb = key + b * NL;
  int ibase = blockIdx.x * 1024;
  unsigned long long ki[4];
#pragma unroll
  for (int k = 0; k < 4; ++k) ki[k] = kb[ibase + k * 256 + tid];
  int j0 = blockIdx.y * 512;
  tile[tid] = kb[j0 + tid];
  tile[tid + 256] = kb[j0 + 256 + tid];
  __syncthreads();
  const ulonglong2* t2 = (const ulonglong2*)tile;
  int cnt[4] = {0, 0, 0, 0};
#pragma unroll 8
  for (int jj = 0; jj < 256; ++jj) {
    ulonglong2 p = t2[jj];
#pragma unroll
    for (int k = 0; k < 4; ++k) {
      cnt[k] += (p.x < ki[k]) ? 1 : 0;
      cnt[k] += (p.y < ki[k]) ? 1 : 0;
    }
  }
#pragma unroll
  for (int k = 0; k < 4; ++k)
    atomicAdd(&rank[b * NL + ibase + k * 256 + tid], cnt[k]);
}

// Kernel 3: mask, w = exp(s - smax) (0 for keep), order inversion, and
// deterministic per-block Z partials (no fp atomics). 256 blocks x 256.
__global__ void __launch_bounds__(256) k_mid(const float* __restrict__ ax,
                                             const float* __restrict__ ay,
                                             const float* __restrict__ alpha,
                                             const float* __restrict__ beta,
                                             const int* __restrict__ rank,
                                             const unsigned* __restrict__ smaxu,
                                             float* __restrict__ w,
                                             float* __restrict__ mask_out,
                                             int* __restrict__ order,
                                             float* __restrict__ Zpart) {
  int gid = blockIdx.x * 256 + threadIdx.x;
  int b = gid >> 12;
  int l = gid & (NL - 1);
  int r = rank[gid];
  float s = __fadd_rn(__fmul_rn(alpha[b], ax[gid]), __fmul_rn(beta[b], ay[gid]));
  __builtin_nontemporal_store((r < NKEEP) ? 1.0f : 0.0f, &mask_out[gid]);
  unsigned SU = smaxu[b];
  float smax = (SU & 0x80000000u) ? __uint_as_float(SU ^ 0x80000000u)
                                  : __uint_as_float(~SU);
  float wi = (r >= NKEEP) ? expf(s - smax) : 0.0f;
  w[gid] = wi;
  order[b * NL + r] = l;
  float zs = wi;
#pragma unroll
  for (int d = 1; d < 64; d <<= 1) zs += __shfl_xor(zs, d, 64);
  __shared__ float zred[4];
  if ((threadIdx.x & 63) == 0) zred[threadIdx.x >> 6] = zs;
  __syncthreads();
  if (threadIdx.x == 0)
    Zpart[blockIdx.x] = (zred[0] + zred[1]) + (zred[2] + zred[3]);
}

// Kernel 4: the permute, output-centric. Block owns 32 consecutive OUTPUT
// positions: gathered CACHED reads (tok allocates in L3 -> hot across
// replays; 16 independent loads in flight/thread), NONTEMPORAL streaming
// 64 KB writes (sel never re-read -> don't evict tok from L3). Positions
// >= NKEEP accumulate w-weighted rows into partial slabs. grid (128, NB).
__global__ void __launch_bounds__(256) k_perm(const f32x4* __restrict__ tok,
                                              const int* __restrict__ order,
                                              const float* __restrict__ w,
                                              f32x4* __restrict__ sel,
                                              f32x4* __restrict__ partial) {
  int b = blockIdx.y;
  int bx = blockIdx.x;
  int p0 = bx * 32;
  int tid = threadIdx.x;
  int col = tid & 127;
  int g = tid >> 7;            // rows p0+g*16 .. p0+g*16+15
  __shared__ int ssrc[32];
  __shared__ float swt[32];
  __shared__ float accsh[512];
  if (tid < 32) {
    int p = p0 + tid;
    int src = order[b * NL + p];
    ssrc[tid] = src;
    swt[tid] = w[b * NL + src];    // 0 for keep rows
  }
  __syncthreads();

  const f32x4* tb = tok + (size_t)b * NL * NC4 + col;
  f32x4 v[16];
#pragma unroll
  for (int k = 0; k < 16; ++k)
    v[k] = tb[(size_t)ssrc[g * 16 + k] * NC4];

  f32x4* sb = sel + (size_t)b * NKEEP * NC4 + col;
  float a0 = 0.f, a1 = 0.f, a2 = 0.f, a3 = 0.f;
#pragma unroll
  for (int k = 0; k < 16; ++k) {
    int p = p0 + g * 16 + k;
    if (p < NKEEP) {
      __builtin_nontemporal_store(v[k], &sb[(size_t)p * NC4]);  // streaming
    } else {
      float wk = swt[g * 16 + k];
      a0 = fmaf(wk, v[k].x, a0);
      a1 = fmaf(wk, v[k].y, a1);
      a2 = fmaf(wk, v[k].z, a2);
      a3 = fmaf(wk, v[k].w, a3);
    }
  }

  if (bx >= KEEPB) {                        // uniform per block
    if (g == 1) {
      accsh[col * 4 + 0] = a0; accsh[col * 4 + 1] = a1;
      accsh[col * 4 + 2] = a2; accsh[col * 4 + 3] = a3;
    }
    __syncthreads();
    if (g == 0) {
      f32x4 o;
      o.x = a0 + accsh[col * 4 + 0];
      o.y = a1 + accsh[col * 4 + 1];
      o.z = a2 + accsh[col * 4 + 2];
      o.w = a3 + accsh[col * 4 + 3];
      partial[(size_t)(b * NTAILB + (bx - KEEPB)) * 128 + col] = o;
    }
  }
}

// Kernel 5: extra = (sum of 52 partials) / (sum of 16 Z partials). 16 x 512.
__global__ void __launch_bounds__(512) k_back(const float* __restrict__ partial,
                                              const float* __restrict__ Zpart,
                                              float* __restrict__ extra) {
  int b = blockIdx.x;
  int c = threadIdx.x;    // 0..511
  float Zb = 0.0f;
#pragma unroll
  for (int k = 0; k < 16; ++k) Zb += Zpart[b * 16 + k];
  const float* p = partial + (size_t)b * NTAILB * 512 + c;
  float a0 = 0.f, a1 = 0.f, a2 = 0.f, a3 = 0.f;
#pragma unroll
  for (int j = 0; j < NTAILB; j += 4) {
    a0 += p[(size_t)(j + 0) * 512];
    a1 += p[(size_t)(j + 1) * 512];
    a2 += p[(size_t)(j + 2) * 512];
    a3 += p[(size_t)(j + 3) * 512];
  }
  extra[b * NC + c] = ((a0 + a1) + (a2 + a3)) / Zb;
}

extern "C" void kernel_launch(void* const* d_in, const int* in_sizes, int n_in,
                              void* d_out, int out_size, void* d_ws, size_t ws_size,
                              hipStream_t stream) {
  (void)in_sizes; (void)n_in; (void)out_size; (void)ws_size;
  const f32x4* tok = (const f32x4*)d_in[0];
  const float* ax = (const float*)d_in[1];
  const float* ay = (const float*)d_in[2];

  unsigned long long* key = (unsigned long long*)d_ws;
  int* rank = (int*)((char*)d_ws + 524288);
  float* w = (float*)((char*)d_ws + 786432);
  int* order = (int*)((char*)d_ws + 1048576);
  f32x4* partial = (f32x4*)((char*)d_ws + 1310720);
  float* scalars = (float*)((char*)d_ws + 3145728);
  float* alpha = scalars;
  float* beta = scalars + 16;
  unsigned* smaxu = (unsigned*)(scalars + 32);
  float* Zpart = scalars + 48;

  float* out = (float*)d_out;
  f32x4* sel = (f32x4*)out;                         // [16][2458][512]
  float* extra = out + (size_t)NB * NKEEP * NC;     // [16][1][512]
  float* mask = extra + (size_t)NB * NC;            // [16][4096]

  k_front<<<NB, 1024, 0, stream>>>(ax, ay, key, rank, alpha, beta, smaxu);
  k_rank<<<dim3(4, 8, NB), 256, 0, stream>>>(key, rank);
  k_mid<<<256, 256, 0, stream>>>(ax, ay, alpha, beta, rank, smaxu, w, mask, order, Zpart);
  k_perm<<<dim3(128, NB), 256, 0, stream>>>(tok, order, w, sel, partial);
  k_back<<<NB, 512, 0, stream>>>((const float*)partial, Zpart, extra);
}

// Round 8
// 67.554 us; speedup vs baseline: 1.0043x; 1.0043x over previous
//
#include <hip/hip_runtime.h>
#include <math.h>

#define NB 16
#define NL 4096
#define NC 512
#define NC4 128          // NC/4 float4 per row
#define NKEEP 2458       // ceil(4096*0.6)
#define KEEPB 76         // first k_perm block with tail rows (76*32 = 2432)
#define NTAILB 52        // 128 - 76 partial slots per batch

typedef float f32x4 __attribute__((ext_vector_type(4)));

// ---------------- ws layout ----------------
// key     u64 [NB][NL]        @ 0        (512 KB)  raw composite keys
// skey    u64 [NB][8][512]    @ 524288   (512 KB)  per-chunk ascending-sorted
// w       f32 [NB][NL]        @ 1048576  (256 KB)  unnormalized exp, 0 for keep
// order   i32 [NB][NL]        @ 1310720  (256 KB)  inverse permutation
// partial f32 [NB][52][512]   @ 1572864  (1.66 MB)
// scalars                     @ 3407872  alpha[16] beta[16] smaxu[16] Zpart[64]

// Kernel 1: per-batch front-end. Wave 0: bit-exact np pairwise mean
// (PW_BLOCKSIZE=128, 8-acc base, butterfly combine) -> alpha/beta.
// Then all 1024 threads: sort keys (mul,mul,add, no FMA), block-reduce
// score max -> smaxu (plain store, no atomics).
__global__ void __launch_bounds__(1024) k_front(const float* __restrict__ ax,
                                                const float* __restrict__ ay,
                                                unsigned long long* __restrict__ key,
                                                float* __restrict__ alpha,
                                                float* __restrict__ beta,
                                                unsigned* __restrict__ smaxu) {
  int b = blockIdx.x;
  int tid = threadIdx.x;
  __shared__ float s_ab[2];
  __shared__ unsigned redmaxu[16];
  if (tid < 64) {
    int lane = tid;
    float sx = 0.0f, sy = 0.0f;
    if (lane < 32) {
      const float* px = ax + b * NL + lane * 128;
      const float* py = ay + b * NL + lane * 128;
      float r[8], q[8];
#pragma unroll
      for (int j = 0; j < 8; ++j) { r[j] = px[j]; q[j] = py[j]; }
      for (int i = 8; i < 128; i += 8) {
#pragma unroll
        for (int j = 0; j < 8; ++j) {
          r[j] = __fadd_rn(r[j], px[i + j]);
          q[j] = __fadd_rn(q[j], py[i + j]);
        }
      }
      sx = __fadd_rn(__fadd_rn(__fadd_rn(r[0], r[1]), __fadd_rn(r[2], r[3])),
                     __fadd_rn(__fadd_rn(r[4], r[5]), __fadd_rn(r[6], r[7])));
      sy = __fadd_rn(__fadd_rn(__fadd_rn(q[0], q[1]), __fadd_rn(q[2], q[3])),
                     __fadd_rn(__fadd_rn(q[4], q[5]), __fadd_rn(q[6], q[7])));
    }
#pragma unroll
    for (int m = 1; m <= 16; m <<= 1) {
      sx = __fadd_rn(sx, __shfl_xor(sx, m, 64));
      sy = __fadd_rn(sy, __shfl_xor(sy, m, 64));
    }
    if (lane == 0) {
      float mx = __fdiv_rn(sx, 4096.0f);
      float my = __fdiv_rn(sy, 4096.0f);
      float cov = __fdiv_rn(my, __fadd_rn(mx, 1e-6f));
      float z = __fsub_rn(1.0f, cov);
      double a = 1.0 / (1.0 + exp(-(double)z));   // correctly-rounded sigmoid
      float af = (float)a;
      alpha[b] = af;
      beta[b] = __fsub_rn(1.0f, af);
      s_ab[0] = af;
      s_ab[1] = __fsub_rn(1.0f, af);
    }
  }
  __syncthreads();
  float af = s_ab[0], bf = s_ab[1];
  unsigned m = 0;   // real max su > 0x80000000 (max score > 0), so 0 is safe
#pragma unroll
  for (int p = 0; p < 4; ++p) {
    int l = p * 1024 + tid;
    int idx = b * NL + l;
    float s = __fadd_rn(__fmul_rn(af, ax[idx]), __fmul_rn(bf, ay[idx]));
    unsigned u = __float_as_uint(s);
    unsigned su = u ^ ((u & 0x80000000u) ? 0xFFFFFFFFu : 0x80000000u);
    key[idx] = ((unsigned long long)(~su) << 32) | (unsigned)l;  // stable descending
    m = (su > m) ? su : m;
  }
#pragma unroll
  for (int d = 1; d < 64; d <<= 1) {
    unsigned o = (unsigned)__shfl_xor((int)m, d, 64);
    m = (o > m) ? o : m;
  }
  if ((tid & 63) == 0) redmaxu[tid >> 6] = m;
  __syncthreads();
  if (tid == 0) {
    unsigned M = redmaxu[0];
#pragma unroll
    for (int k = 1; k < 16; ++k) M = (redmaxu[k] > M) ? redmaxu[k] : M;
    smaxu[b] = M;
  }
}

// Kernel 2: bitonic-sort each 512-key chunk in LDS (ascending u64).
// Keys unique (index tiebreak) -> deterministic. grid (8, NB) x 256.
__global__ void __launch_bounds__(256) k_sort(const unsigned long long* __restrict__ key,
                                              unsigned long long* __restrict__ skey) {
  __shared__ unsigned long long lk[512];
  int b = blockIdx.y;
  int c = blockIdx.x;
  int t = threadIdx.x;
  const unsigned long long* kb = key + (size_t)b * NL + c * 512;
  lk[t] = kb[t];
  lk[t + 256] = kb[t + 256];
  __syncthreads();
  for (int k = 2; k <= 512; k <<= 1) {
    for (int j = k >> 1; j > 0; j >>= 1) {
#pragma unroll
      for (int e = 0; e < 2; ++e) {
        int i = t + e * 256;
        int l = i ^ j;
        if (l > i) {                       // unique owner per disjoint pair
          unsigned long long a = lk[i], bb = lk[l];
          bool up = ((i & k) == 0);
          if ((a > bb) == up) { lk[i] = bb; lk[l] = a; }
        }
      }
      __syncthreads();
    }
  }
  unsigned long long* sb = skey + ((size_t)b * 8 + c) * 512;
  sb[t] = lk[t];
  sb[t + 256] = lk[t + 256];
}

// Kernel 3: rank via 8 branchless lower_bounds in the batch's sorted chunks
// (staged in 32 KB LDS), then mask, w = exp(s - smax), order inversion, and
// per-block Z partials. grid 64 (= 4 blocks/batch) x 1024.
__global__ void __launch_bounds__(1024) k_mid(const float* __restrict__ ax,
                                              const float* __restrict__ ay,
                                              const float* __restrict__ alpha,
                                              const float* __restrict__ beta,
                                              const unsigned long long* __restrict__ skey,
                                              const unsigned* __restrict__ smaxu,
                                              float* __restrict__ w,
                                              float* __restrict__ mask_out,
                                              int* __restrict__ order,
                                              float* __restrict__ Zpart) {
  __shared__ unsigned long long lsk[4096];   // 32 KB
  __shared__ float zred[16];
  int bx = blockIdx.x;
  int b = bx >> 2;
  int q = bx & 3;
  int t = threadIdx.x;
  const unsigned long long* sb = skey + (size_t)b * NL;
#pragma unroll
  for (int k = 0; k < 4; ++k) lsk[k * 1024 + t] = sb[k * 1024 + t];
  __syncthreads();

  int l = q * 1024 + t;
  int gid = b * NL + l;
  float s = __fadd_rn(__fmul_rn(alpha[b], ax[gid]), __fmul_rn(beta[b], ay[gid]));
  unsigned u = __float_as_uint(s);
  unsigned su = u ^ ((u & 0x80000000u) ? 0xFFFFFFFFu : 0x80000000u);
  unsigned long long ki = ((unsigned long long)(~su) << 32) | (unsigned)l;

  int r = 0;
#pragma unroll
  for (int c = 0; c < 8; ++c) {
    const unsigned long long* base = lsk + c * 512;
    int pos = 0;
#pragma unroll
    for (int step = 512; step >= 1; step >>= 1) {
      int cand = pos + step;
      if (cand <= 512 && base[cand - 1] < ki) pos = cand;
    }
    r += pos;   // count of keys < ki in this chunk
  }

  mask_out[gid] = (r < NKEEP) ? 1.0f : 0.0f;
  unsigned SU = smaxu[b];
  float smax = (SU & 0x80000000u) ? __uint_as_float(SU ^ 0x80000000u)
                                  : __uint_as_float(~SU);
  float wi = (r >= NKEEP) ? expf(s - smax) : 0.0f;
  w[gid] = wi;
  order[b * NL + r] = l;

  float zs = wi;
#pragma unroll
  for (int d = 1; d < 64; d <<= 1) zs += __shfl_xor(zs, d, 64);
  if ((t & 63) == 0) zred[t >> 6] = zs;
  __syncthreads();
  if (t == 0) {
    float z = 0.0f;
#pragma unroll
    for (int k = 0; k < 16; ++k) z += zred[k];
    Zpart[bx] = z;
  }
}

// Kernel 4: the permute, output-centric. Block owns 32 consecutive OUTPUT
// positions: gathered cached reads (16 independent loads in flight/thread),
// streaming 64 KB contiguous writes. Positions >= NKEEP accumulate
// w-weighted rows into partial slabs. grid (128, NB) x 256.
__global__ void __launch_bounds__(256) k_perm(const f32x4* __restrict__ tok,
                                              const int* __restrict__ order,
                                              const float* __restrict__ w,
                                              f32x4* __restrict__ sel,
                                              f32x4* __restrict__ partial) {
  int b = blockIdx.y;
  int bx = blockIdx.x;
  int p0 = bx * 32;
  int tid = threadIdx.x;
  int col = tid & 127;
  int g = tid >> 7;            // rows p0+g*16 .. p0+g*16+15
  __shared__ int ssrc[32];
  __shared__ float swt[32];
  __shared__ float accsh[512];
  if (tid < 32) {
    int p = p0 + tid;
    int src = order[b * NL + p];
    ssrc[tid] = src;
    swt[tid] = w[b * NL + src];    // 0 for keep rows
  }
  __syncthreads();

  const f32x4* tb = tok + (size_t)b * NL * NC4 + col;
  f32x4 v[16];
#pragma unroll
  for (int k = 0; k < 16; ++k)
    v[k] = tb[(size_t)ssrc[g * 16 + k] * NC4];

  f32x4* sb = sel + (size_t)b * NKEEP * NC4 + col;
  float a0 = 0.f, a1 = 0.f, a2 = 0.f, a3 = 0.f;
#pragma unroll
  for (int k = 0; k < 16; ++k) {
    int p = p0 + g * 16 + k;
    if (p < NKEEP) {
      sb[(size_t)p * NC4] = v[k];          // streaming contiguous writes
    } else {
      float wk = swt[g * 16 + k];
      a0 = fmaf(wk, v[k].x, a0);
      a1 = fmaf(wk, v[k].y, a1);
      a2 = fmaf(wk, v[k].z, a2);
      a3 = fmaf(wk, v[k].w, a3);
    }
  }

  if (bx >= KEEPB) {                        // uniform per block
    if (g == 1) {
      accsh[col * 4 + 0] = a0; accsh[col * 4 + 1] = a1;
      accsh[col * 4 + 2] = a2; accsh[col * 4 + 3] = a3;
    }
    __syncthreads();
    if (g == 0) {
      f32x4 o;
      o.x = a0 + accsh[col * 4 + 0];
      o.y = a1 + accsh[col * 4 + 1];
      o.z = a2 + accsh[col * 4 + 2];
      o.w = a3 + accsh[col * 4 + 3];
      partial[(size_t)(b * NTAILB + (bx - KEEPB)) * 128 + col] = o;
    }
  }
}

// Kernel 5: extra = (sum of 52 partials) / (sum of 4 Z partials). 16 x 512.
__global__ void __launch_bounds__(512) k_back(const float* __restrict__ partial,
                                              const float* __restrict__ Zpart,
                                              float* __restrict__ extra) {
  int b = blockIdx.x;
  int c = threadIdx.x;    // 0..511
  float Zb = 0.0f;
#pragma unroll
  for (int k = 0; k < 4; ++k) Zb += Zpart[b * 4 + k];
  const float* p = partial + (size_t)b * NTAILB * 512 + c;
  float a0 = 0.f, a1 = 0.f, a2 = 0.f, a3 = 0.f;
#pragma unroll
  for (int j = 0; j < NTAILB; j += 4) {
    a0 += p[(size_t)(j + 0) * 512];
    a1 += p[(size_t)(j + 1) * 512];
    a2 += p[(size_t)(j + 2) * 512];
    a3 += p[(size_t)(j + 3) * 512];
  }
  extra[b * NC + c] = ((a0 + a1) + (a2 + a3)) / Zb;
}

extern "C" void kernel_launch(void* const* d_in, const int* in_sizes, int n_in,
                              void* d_out, int out_size, void* d_ws, size_t ws_size,
                              hipStream_t stream) {
  (void)in_sizes; (void)n_in; (void)out_size; (void)ws_size;
  const f32x4* tok = (const f32x4*)d_in[0];
  const float* ax = (const float*)d_in[1];
  const float* ay = (const float*)d_in[2];

  unsigned long long* key = (unsigned long long*)d_ws;
  unsigned long long* skey = (unsigned long long*)((char*)d_ws + 524288);
  float* w = (float*)((char*)d_ws + 1048576);
  int* order = (int*)((char*)d_ws + 1310720);
  f32x4* partial = (f32x4*)((char*)d_ws + 1572864);
  float* scalars = (float*)((char*)d_ws + 3407872);
  float* alpha = scalars;
  float* beta = scalars + 16;
  unsigned* smaxu = (unsigned*)(scalars + 32);
  float* Zpart = scalars + 48;

  float* out = (float*)d_out;
  f32x4* sel = (f32x4*)out;                         // [16][2458][512]
  float* extra = out + (size_t)NB * NKEEP * NC;     // [16][1][512]
  float* mask = extra + (size_t)NB * NC;            // [16][4096]

  k_front<<<NB, 1024, 0, stream>>>(ax, ay, key, alpha, beta, smaxu);
  k_sort<<<dim3(8, NB), 256, 0, stream>>>(key, skey);
  k_mid<<<64, 1024, 0, stream>>>(ax, ay, alpha, beta, skey, smaxu, w, mask, order, Zpart);
  k_perm<<<dim3(128, NB), 256, 0, stream>>>(tok, order, w, sel, partial);
  k_back<<<NB, 512, 0, stream>>>((const float*)partial, Zpart, extra);
}

// Round 9
// 63.901 us; speedup vs baseline: 1.0617x; 1.0572x over previous
//
#include <hip/hip_runtime.h>
#include <math.h>

#define NB 16
#define NL 4096
#define NC 512
#define NC4 128          // NC/4 float4 per row
#define NKEEP 2458       // ceil(4096*0.6)
#define KEEPB 76         // first k_perm block with tail rows (76*32 = 2432)
#define NTAILB 52        // 128 - 76 partial slots per batch

typedef float f32x4 __attribute__((ext_vector_type(4)));

// ---------------- ws layout ----------------
// skey    u64 [NB][8][512]    @ 0        (512 KB)  per-chunk ascending-sorted keys
// w       f32 [NB][NL]        @ 524288   (256 KB)  unnormalized exp, 0 for keep
// order   i32 [NB][NL]        @ 786432   (256 KB)  inverse permutation
// partial f32 [NB][52][512]   @ 1048576  (1.66 MB)
// Zpart   f32 [128]           @ 2883584

// Kernel 1: per-chunk sort, self-contained. Wave 0 recomputes the batch's
// alpha with the bit-exact np pairwise-mean code (deterministic, redundant
// across the batch's 8 blocks). All 256 threads then build the chunk's 512
// composite keys (mul,mul,add, no FMA) in LDS, bitonic-sort ascending
// (keys unique via index tiebreak), write skey. grid (8, NB) x 256.
__global__ void __launch_bounds__(256) k_sort(const float* __restrict__ ax,
                                              const float* __restrict__ ay,
                                              unsigned long long* __restrict__ skey) {
  __shared__ unsigned long long lk[512];
  __shared__ float s_ab[2];
  int b = blockIdx.y;
  int c = blockIdx.x;
  int t = threadIdx.x;

  if (t < 64) {
    int lane = t;
    float sx = 0.0f, sy = 0.0f;
    if (lane < 32) {
      const float* px = ax + b * NL + lane * 128;
      const float* py = ay + b * NL + lane * 128;
      float r[8], q[8];
#pragma unroll
      for (int j = 0; j < 8; ++j) { r[j] = px[j]; q[j] = py[j]; }
      for (int i = 8; i < 128; i += 8) {
#pragma unroll
        for (int j = 0; j < 8; ++j) {
          r[j] = __fadd_rn(r[j], px[i + j]);
          q[j] = __fadd_rn(q[j], py[i + j]);
        }
      }
      sx = __fadd_rn(__fadd_rn(__fadd_rn(r[0], r[1]), __fadd_rn(r[2], r[3])),
                     __fadd_rn(__fadd_rn(r[4], r[5]), __fadd_rn(r[6], r[7])));
      sy = __fadd_rn(__fadd_rn(__fadd_rn(q[0], q[1]), __fadd_rn(q[2], q[3])),
                     __fadd_rn(__fadd_rn(q[4], q[5]), __fadd_rn(q[6], q[7])));
    }
#pragma unroll
    for (int m = 1; m <= 16; m <<= 1) {
      sx = __fadd_rn(sx, __shfl_xor(sx, m, 64));
      sy = __fadd_rn(sy, __shfl_xor(sy, m, 64));
    }
    if (lane == 0) {
      float mx = __fdiv_rn(sx, 4096.0f);
      float my = __fdiv_rn(sy, 4096.0f);
      float cov = __fdiv_rn(my, __fadd_rn(mx, 1e-6f));
      float z = __fsub_rn(1.0f, cov);
      double a = 1.0 / (1.0 + exp(-(double)z));   // correctly-rounded sigmoid
      float af = (float)a;
      s_ab[0] = af;
      s_ab[1] = __fsub_rn(1.0f, af);
    }
  }
  __syncthreads();
  float af = s_ab[0], bf = s_ab[1];

#pragma unroll
  for (int e = 0; e < 2; ++e) {
    int l = c * 512 + t + e * 256;
    int idx = b * NL + l;
    float s = __fadd_rn(__fmul_rn(af, ax[idx]), __fmul_rn(bf, ay[idx]));
    unsigned u = __float_as_uint(s);
    unsigned su = u ^ ((u & 0x80000000u) ? 0xFFFFFFFFu : 0x80000000u);
    lk[t + e * 256] = ((unsigned long long)(~su) << 32) | (unsigned)l;
  }
  __syncthreads();

  for (int k = 2; k <= 512; k <<= 1) {
    for (int j = k >> 1; j > 0; j >>= 1) {
#pragma unroll
      for (int e = 0; e < 2; ++e) {
        int i = t + e * 256;
        int l = i ^ j;
        if (l > i) {                       // unique owner per disjoint pair
          unsigned long long a = lk[i], bb = lk[l];
          bool up = ((i & k) == 0);
          if ((a > bb) == up) { lk[i] = bb; lk[l] = a; }
        }
      }
      __syncthreads();
    }
  }
  unsigned long long* sb = skey + ((size_t)b * 8 + c) * 512;
  sb[t] = lk[t];
  sb[t + 256] = lk[t + 256];
}

// Kernel 2: rank via 8 branchless lower_bounds in the batch's sorted chunks
// (staged in 32 KB LDS); smax decoded from the global min key (= max score);
// mask, w = exp(s - smax), order inversion, per-block Z partial.
// grid 128 (= 8 blocks/batch) x 512.
__global__ void __launch_bounds__(512) k_mid(const float* __restrict__ ax,
                                             const float* __restrict__ ay,
                                             const unsigned long long* __restrict__ skey,
                                             float* __restrict__ w,
                                             float* __restrict__ mask_out,
                                             int* __restrict__ order,
                                             float* __restrict__ Zpart) {
  __shared__ unsigned long long lsk[4096];   // 32 KB
  __shared__ float zred[8];
  int bx = blockIdx.x;
  int b = bx >> 3;
  int q = bx & 7;
  int t = threadIdx.x;
  const unsigned long long* sb = skey + (size_t)b * NL;
#pragma unroll
  for (int k = 0; k < 8; ++k) lsk[k * 512 + t] = sb[k * 512 + t];
  __syncthreads();

  // smax = score of the global min key (keys ascend <=> scores descend)
  unsigned long long kmin = lsk[0];
#pragma unroll
  for (int c = 1; c < 8; ++c) {
    unsigned long long h = lsk[c * 512];
    kmin = (h < kmin) ? h : kmin;
  }
  unsigned su0 = ~(unsigned)(kmin >> 32);
  float smax = (su0 & 0x80000000u) ? __uint_as_float(su0 ^ 0x80000000u)
                                   : __uint_as_float(~su0);

  // recompute this element's key (bit-identical to k_sort's: alpha path is
  // deterministic, formula identical)
  int l = q * 512 + t;
  int gid = b * NL + l;
  // recompute alpha from scores? No: decode from keys is impossible for
  // alpha; instead recompute s from the SAME alpha used in k_sort. We
  // recover alpha exactly: it is not stored, so recompute s via key lookup
  // is not possible -- but s itself can be decoded from OUR OWN key, which
  // is lsk[?] at unknown position. Instead: recompute alpha cheaply here
  // is wrong; so we decode s from the key we find by searching for the
  // tiebreak index. Simpler: recompute key from ax/ay requires alpha.
  // Solution: alpha is decodable from any two known scores? No. So:
  // we carry s through the key itself -- find OUR key by index? The key
  // embeds l in low bits but position is unknown. HOWEVER rank search
  // only needs ki; we can reconstruct ki from s, and s from... 
  // => simplest correct path: recompute alpha exactly as k_sort did.
  __shared__ float s_ab[2];
  if (t < 64) {
    int lane = t;
    float sx = 0.0f, sy = 0.0f;
    if (lane < 32) {
      const float* px = ax + b * NL + lane * 128;
      const float* py = ay + b * NL + lane * 128;
      float r[8], qq[8];
#pragma unroll
      for (int j = 0; j < 8; ++j) { r[j] = px[j]; qq[j] = py[j]; }
      for (int i = 8; i < 128; i += 8) {
#pragma unroll
        for (int j = 0; j < 8; ++j) {
          r[j] = __fadd_rn(r[j], px[i + j]);
          qq[j] = __fadd_rn(qq[j], py[i + j]);
        }
      }
      sx = __fadd_rn(__fadd_rn(__fadd_rn(r[0], r[1]), __fadd_rn(r[2], r[3])),
                     __fadd_rn(__fadd_rn(r[4], r[5]), __fadd_rn(r[6], r[7])));
      sy = __fadd_rn(__fadd_rn(__fadd_rn(qq[0], qq[1]), __fadd_rn(qq[2], qq[3])),
                     __fadd_rn(__fadd_rn(qq[4], qq[5]), __fadd_rn(qq[6], qq[7])));
    }
#pragma unroll
    for (int m = 1; m <= 16; m <<= 1) {
      sx = __fadd_rn(sx, __shfl_xor(sx, m, 64));
      sy = __fadd_rn(sy, __shfl_xor(sy, m, 64));
    }
    if (lane == 0) {
      float mx = __fdiv_rn(sx, 4096.0f);
      float my = __fdiv_rn(sy, 4096.0f);
      float cov = __fdiv_rn(my, __fadd_rn(mx, 1e-6f));
      float z = __fsub_rn(1.0f, cov);
      double a = 1.0 / (1.0 + exp(-(double)z));
      float af = (float)a;
      s_ab[0] = af;
      s_ab[1] = __fsub_rn(1.0f, af);
    }
  }
  __syncthreads();
  float s = __fadd_rn(__fmul_rn(s_ab[0], ax[gid]), __fmul_rn(s_ab[1], ay[gid]));
  unsigned u = __float_as_uint(s);
  unsigned su = u ^ ((u & 0x80000000u) ? 0xFFFFFFFFu : 0x80000000u);
  unsigned long long ki = ((unsigned long long)(~su) << 32) | (unsigned)l;

  int r = 0;
#pragma unroll
  for (int c = 0; c < 8; ++c) {
    const unsigned long long* base = lsk + c * 512;
    int pos = 0;
#pragma unroll
    for (int step = 512; step >= 1; step >>= 1) {
      int cand = pos + step;
      if (cand <= 512 && base[cand - 1] < ki) pos = cand;
    }
    r += pos;   // count of keys < ki in this chunk
  }

  mask_out[gid] = (r < NKEEP) ? 1.0f : 0.0f;
  float wi = (r >= NKEEP) ? expf(s - smax) : 0.0f;
  w[gid] = wi;
  order[b * NL + r] = l;

  float zs = wi;
#pragma unroll
  for (int d = 1; d < 64; d <<= 1) zs += __shfl_xor(zs, d, 64);
  if ((t & 63) == 0) zred[t >> 6] = zs;
  __syncthreads();
  if (t == 0) {
    float z = 0.0f;
#pragma unroll
    for (int k = 0; k < 8; ++k) z += zred[k];
    Zpart[bx] = z;
  }
}

// Kernel 3: the permute, output-centric. Block owns 32 consecutive OUTPUT
// positions: gathered cached reads (16 independent loads in flight/thread),
// streaming 64 KB contiguous writes. Positions >= NKEEP accumulate
// w-weighted rows into partial slabs. grid (128, NB) x 256.
__global__ void __launch_bounds__(256) k_perm(const f32x4* __restrict__ tok,
                                              const int* __restrict__ order,
                                              const float* __restrict__ w,
                                              f32x4* __restrict__ sel,
                                              f32x4* __restrict__ partial) {
  int b = blockIdx.y;
  int bx = blockIdx.x;
  int p0 = bx * 32;
  int tid = threadIdx.x;
  int col = tid & 127;
  int g = tid >> 7;            // rows p0+g*16 .. p0+g*16+15
  __shared__ int ssrc[32];
  __shared__ float swt[32];
  __shared__ float accsh[512];
  if (tid < 32) {
    int p = p0 + tid;
    int src = order[b * NL + p];
    ssrc[tid] = src;
    swt[tid] = w[b * NL + src];    // 0 for keep rows
  }
  __syncthreads();

  const f32x4* tb = tok + (size_t)b * NL * NC4 + col;
  f32x4 v[16];
#pragma unroll
  for (int k = 0; k < 16; ++k)
    v[k] = tb[(size_t)ssrc[g * 16 + k] * NC4];

  f32x4* sb = sel + (size_t)b * NKEEP * NC4 + col;
  float a0 = 0.f, a1 = 0.f, a2 = 0.f, a3 = 0.f;
#pragma unroll
  for (int k = 0; k < 16; ++k) {
    int p = p0 + g * 16 + k;
    if (p < NKEEP) {
      sb[(size_t)p * NC4] = v[k];          // streaming contiguous writes
    } else {
      float wk = swt[g * 16 + k];
      a0 = fmaf(wk, v[k].x, a0);
      a1 = fmaf(wk, v[k].y, a1);
      a2 = fmaf(wk, v[k].z, a2);
      a3 = fmaf(wk, v[k].w, a3);
    }
  }

  if (bx >= KEEPB) {                        // uniform per block
    if (g == 1) {
      accsh[col * 4 + 0] = a0; accsh[col * 4 + 1] = a1;
      accsh[col * 4 + 2] = a2; accsh[col * 4 + 3] = a3;
    }
    __syncthreads();
    if (g == 0) {
      f32x4 o;
      o.x = a0 + accsh[col * 4 + 0];
      o.y = a1 + accsh[col * 4 + 1];
      o.z = a2 + accsh[col * 4 + 2];
      o.w = a3 + accsh[col * 4 + 3];
      partial[(size_t)(b * NTAILB + (bx - KEEPB)) * 128 + col] = o;
    }
  }
}

// Kernel 4: extra = (sum of 52 partials) / (sum of 8 Z partials). 16 x 512.
__global__ void __launch_bounds__(512) k_back(const float* __restrict__ partial,
                                              const float* __restrict__ Zpart,
                                              float* __restrict__ extra) {
  int b = blockIdx.x;
  int c = threadIdx.x;    // 0..511
  float Zb = 0.0f;
#pragma unroll
  for (int k = 0; k < 8; ++k) Zb += Zpart[b * 8 + k];
  const float* p = partial + (size_t)b * NTAILB * 512 + c;
  float a0 = 0.f, a1 = 0.f, a2 = 0.f, a3 = 0.f;
#pragma unroll
  for (int j = 0; j < NTAILB; j += 4) {
    a0 += p[(size_t)(j + 0) * 512];
    a1 += p[(size_t)(j + 1) * 512];
    a2 += p[(size_t)(j + 2) * 512];
    a3 += p[(size_t)(j + 3) * 512];
  }
  extra[b * NC + c] = ((a0 + a1) + (a2 + a3)) / Zb;
}

extern "C" void kernel_launch(void* const* d_in, const int* in_sizes, int n_in,
                              void* d_out, int out_size, void* d_ws, size_t ws_size,
                              hipStream_t stream) {
  (void)in_sizes; (void)n_in; (void)out_size; (void)ws_size;
  const f32x4* tok = (const f32x4*)d_in[0];
  const float* ax = (const float*)d_in[1];
  const float* ay = (const float*)d_in[2];

  unsigned long long* skey = (unsigned long long*)d_ws;
  float* w = (float*)((char*)d_ws + 524288);
  int* order = (int*)((char*)d_ws + 786432);
  f32x4* partial = (f32x4*)((char*)d_ws + 1048576);
  float* Zpart = (float*)((char*)d_ws + 2883584);

  float* out = (float*)d_out;
  f32x4* sel = (f32x4*)out;                         // [16][2458][512]
  float* extra = out + (size_t)NB * NKEEP * NC;     // [16][1][512]
  float* mask = extra + (size_t)NB * NC;            // [16][4096]

  k_sort<<<dim3(8, NB), 256, 0, stream>>>(ax, ay, skey);
  k_mid<<<128, 512, 0, stream>>>(ax, ay, skey, w, mask, order, Zpart);
  k_perm<<<dim3(128, NB), 256, 0, stream>>>(tok, order, w, sel, partial);
  k_back<<<NB, 512, 0, stream>>>((const float*)partial, Zpart, extra);
}